// Round 9
// baseline (3322.132 us; speedup 1.0000x reference)
//
#include <hip/hip_runtime.h>

#define T_STEPS 200
#define BATCH   32
#define HID     1024
#define NWG     256
#define NTHR    512
#define HB      (BATCH * HID)   /* 32768 words per h slot */

typedef _Float16 half8 __attribute__((ext_vector_type(8)));
typedef float    f32x4 __attribute__((ext_vector_type(4)));
typedef unsigned long long u64;

#define RLX __ATOMIC_RELAXED
#define AGT __HIP_MEMORY_SCOPE_AGENT
#define TAGMASK 0xFFFF0000FFFF0000ull

static __device__ __forceinline__ unsigned short f16bits(_Float16 v) {
    union { _Float16 f; unsigned short u; } c; c.f = v; return c.u;
}

// uncached 16B store (two 8B agent atomics) for the y0m producer path
__device__ __forceinline__ void st_coh16(_Float16* p, half8 v) {
    union { half8 h; u64 u[2]; } r; r.h = v;
    u64* q = (u64*)p;
    __hip_atomic_store(q,     r.u[0], RLX, AGT);
    __hip_atomic_store(q + 1, r.u[1], RLX, AGT);
}

__device__ __forceinline__ half8 cvt8(const float* p) {
    f32x4 lo = *(const f32x4*)p;
    f32x4 hi = *(const f32x4*)(p + 4);
    half8 a;
    a[0] = (_Float16)lo[0]; a[1] = (_Float16)lo[1];
    a[2] = (_Float16)lo[2]; a[3] = (_Float16)lo[3];
    a[4] = (_Float16)hi[0]; a[5] = (_Float16)hi[1];
    a[6] = (_Float16)hi[2]; a[7] = (_Float16)hi[3];
    return a;
}

// h exchange word: (tag << 16) | f16bits.  h_s lives in slot s&1 tagged s+1.
__global__ void init_k(const float* __restrict__ h0,
                       unsigned* __restrict__ h0w, unsigned* __restrict__ h1w,
                       unsigned* __restrict__ flag0) {
    int i = blockIdx.x * blockDim.x + threadIdx.x;
    if (i < HB) {
        h0w[i]      = (1u << 16) | f16bits((_Float16)h0[i]);   // slot0: h_0, tag 1
        h0w[HB + i] = 0u;                                      // slot1: invalid
        h1w[i]      = (1u << 16) | f16bits((_Float16)h0[HB + i]);
        h1w[HB + i] = 0u;
    }
    if (blockIdx.x == 0 && threadIdx.x < 128) flag0[threadIdx.x * 32] = 0u;
}

// Self-timed LSTM, tagged h exchange (detect==load, no ack, no h flag).
// 256 WGs x 512 thr; WGs 0-127 layer 0, 128-255 layer 1; weights in LDS.
// Producer: act stages tagged words to LDS; a NON-POLLING wave fires 2x8B
// atomic stores per lane (fire-and-forget). Consumer: 64 u64 loads up-front,
// per-chunk tag validation, stale-chunk-only re-poll with FMA backoff,
// chunk-interleaved MFMA. Slot safety by tag transitivity (see R8 proof).
// y0m keeps cached reads + store->ack->flag0 (feed-forward). No fences.
__global__ __launch_bounds__(NTHR, 1) void lstm_main(
    const float* __restrict__ x, const float* __restrict__ c0,
    const float* __restrict__ Wih, const float* __restrict__ Whh,
    const float* __restrict__ bih, const float* __restrict__ bhh,
    const float* __restrict__ mi, const float* __restrict__ mo,
    float* __restrict__ out,
    _Float16* __restrict__ y0m, unsigned* __restrict__ h0w,
    unsigned* __restrict__ h1w, unsigned* __restrict__ flag0)
{
    __shared__ _Float16 W_s[32 * 2048];     // 128 KB
    __shared__ float scr[8][2][16][17];     // per-(kq,mm) partial gate tiles
    __shared__ float c_s[BATCH][8];         // persistent cell state
    __shared__ alignas(16) _Float16 st_y[BATCH][8];    // y0*mask staging (L0)
    __shared__ alignas(16) unsigned st_hw[BATCH][8];   // tagged h words staging
    __shared__ float st_mi[BATCH][8];       // next-tick mi staging (L0)
    __shared__ float st_o[BATCH][8];        // h staging for out (L1)

    const int bid   = blockIdx.x;
    const int layer = bid >> 7;
    const int wgl   = bid & 127;
    const int tid   = threadIdx.x;

    // ---- one-time: stage weight slice into LDS (f16, XOR-swizzled) ----
    const float* WihL = Wih + (size_t)layer * 4 * HID * HID;
    const float* WhhL = Whh + (size_t)layer * 4 * HID * HID;
    for (int idx = tid; idx < 32 * 2048; idx += NTHR) {
        int r = idx >> 11, k = idx & 2047;
        int grow = (r >> 3) * HID + wgl * 8 + (r & 7);
        float v = (k < HID) ? WihL[(size_t)grow * HID + k]
                            : WhhL[(size_t)grow * HID + (k - HID)];
        W_s[idx ^ ((r & 7) << 3)] = (_Float16)v;
    }

    float bias0 = 0.f, bias1 = 0.f, bias2 = 0.f, bias3 = 0.f;
    int b_ = 0, col_ = 0, gcol = 0;
    if (tid < 256) {
        b_ = tid >> 3; col_ = tid & 7; gcol = wgl * 8 + col_;
        bias0 = bih[layer * 4096 + gcol]           + bhh[layer * 4096 + gcol];
        bias1 = bih[layer * 4096 + HID + gcol]     + bhh[layer * 4096 + HID + gcol];
        bias2 = bih[layer * 4096 + 2 * HID + gcol] + bhh[layer * 4096 + 2 * HID + gcol];
        bias3 = bih[layer * 4096 + 3 * HID + gcol] + bhh[layer * 4096 + 3 * HID + gcol];
        c_s[b_][col_] = c0[((size_t)layer * BATCH + b_) * HID + gcol];
    }
    const int ot = tid - 256;                      // waves 4-7 helper index
    const int b2 = (ot >= 0) ? (ot >> 3) : 0, c2 = (ot >= 0) ? (ot & 7) : 0;
    const int gcol2 = wgl * 8 + c2;

    float mo_reg = 0.f;
    if (layer == 0 && ot >= 0) st_mi[b2][c2] = mi[(size_t)b2 * HID + gcol2];   // s=0
    if (layer == 1 && ot >= 0) mo_reg = mo[(size_t)b2 * HID + gcol2];          // s=0
    __syncthreads();

    const int lane = tid & 63, wid = tid >> 6;
    // layer 0: waves 0-3 = h-pollers (kq 2,3) + act; waves 4-7 = x (kq 0,1).
    // layer 1: waves 0-3 = y (kq 0,1) + act; waves 4-7 = h1-pollers (kq 2,3).
    int kq;
    if (layer == 0) kq = (wid < 4) ? (2 + (wid >> 1)) : ((wid - 4) >> 1);
    else            kq = wid >> 1;
    const int mm   = wid & 1;
    const int srow = kq * 2 + mm;
    const int row = lane & 15, bb = mm * 16 + row, ko = (lane >> 4) * 8;

    half8 aF[16];
    if (layer == 0 && kq < 2) {                    // x prefetch for s=0
        const float* xp = x + (size_t)bb * HID + kq * 512 + ko;
        #pragma unroll
        for (int kk = 0; kk < 16; ++kk) aF[kk] = cvt8(xp + kk * 32);
    }

    for (int s = 0; s < T_STEPS; ++s) {
        f32x4 acc0 = {0.f, 0.f, 0.f, 0.f}, acc1 = {0.f, 0.f, 0.f, 0.f};

        if (kq >= 2) {
            // ---- tagged h exchange: load all, validate per chunk, MFMA ----
            const unsigned* __restrict__ hsrc = (layer == 0) ? h0w : h1w;
            const unsigned tg = (unsigned)(s + 1);
            const u64 expect = ((u64)tg << 48) | ((u64)tg << 16);
            const unsigned* basew = hsrc + (s & 1) * HB + bb * 1024
                                  + (kq - 2) * 512 + ko;
            u64 w[64];
            #pragma unroll
            for (int i = 0; i < 64; ++i)
                w[i] = __hip_atomic_load(
                    (const u64*)(basew + (i >> 2) * 32 + (i & 3) * 2), RLX, AGT);
            #pragma unroll
            for (int c = 0; c < 4; ++c) {
                for (;;) {
                    u64 bad = 0;
                    #pragma unroll
                    for (int i = c * 16; i < c * 16 + 16; ++i)
                        bad |= (w[i] & TAGMASK) ^ expect;
                    if (__all(bad == 0)) break;
                    float jj = 1.f;                       // ~60ns backoff
                    #pragma unroll
                    for (int r9 = 0; r9 < 32; ++r9)
                        asm volatile("v_fma_f32 %0,%0,%0,%0" : "+v"(jj));
                    asm volatile("" :: "v"(jj));
                    #pragma unroll
                    for (int i = c * 16; i < c * 16 + 16; ++i)
                        w[i] = __hip_atomic_load(
                            (const u64*)(basew + (i >> 2) * 32 + (i & 3) * 2), RLX, AGT);
                }
                #pragma unroll
                for (int k2 = 0; k2 < 4; ++k2) {
                    const int kk = c * 4 + k2;
                    union { half8 h; unsigned short u[8]; } a;
                    #pragma unroll
                    for (int j = 0; j < 8; ++j)
                        a.u[j] = (unsigned short)(w[kk * 4 + (j >> 1)] >> (32 * (j & 1)));
                    const int k  = kq * 512 + kk * 32 + ko;
                    const int r1 = 16 + row;
                    const half8 bB0 = *(const half8*)&W_s[(row * 2048 + k) ^ ((row & 7) << 3)];
                    const half8 bB1 = *(const half8*)&W_s[(r1 * 2048 + k) ^ ((r1 & 7) << 3)];
                    acc0 = __builtin_amdgcn_mfma_f32_16x16x32_f16(a.h, bB0, acc0, 0, 0, 0);
                    acc1 = __builtin_amdgcn_mfma_f32_16x16x32_f16(a.h, bB1, acc1, 0, 0, 0);
                }
            }
        } else {
            if (layer == 1) {
                // ---- y path: flag0 wait, then cached loads (lines virgin) ----
                const unsigned tgt = (unsigned)(s + 1);
                const unsigned* fa = flag0 + (lane * 2) * 32;
                const unsigned* fb = flag0 + (lane * 2 + 1) * 32;
                for (;;) {
                    unsigned va = __hip_atomic_load(fa, RLX, AGT);
                    unsigned vb = __hip_atomic_load(fb, RLX, AGT);
                    if (__all((va >= tgt) & (vb >= tgt))) break;
                }
                asm volatile("" ::: "memory");
                const _Float16* yp = y0m + ((size_t)s * BATCH + bb) * HID + kq * 512 + ko;
                #pragma unroll
                for (int kk = 0; kk < 16; ++kk) aF[kk] = *(const half8*)(yp + kk * 32);
            }
            // layer 0 x-waves: aF prefetched in previous tail, zero wait
            #pragma unroll
            for (int kk = 0; kk < 16; ++kk) {
                const int k  = kq * 512 + kk * 32 + ko;
                const int r1 = 16 + row;
                const half8 bB0 = *(const half8*)&W_s[(row * 2048 + k) ^ ((row & 7) << 3)];
                const half8 bB1 = *(const half8*)&W_s[(r1 * 2048 + k) ^ ((r1 & 7) << 3)];
                acc0 = __builtin_amdgcn_mfma_f32_16x16x32_f16(aF[kk], bB0, acc0, 0, 0, 0);
                acc1 = __builtin_amdgcn_mfma_f32_16x16x32_f16(aF[kk], bB1, acc1, 0, 0, 0);
            }
        }

        #pragma unroll
        for (int j = 0; j < 4; ++j) {
            scr[srow][0][(lane >> 4) * 4 + j][row] = acc0[j];
            scr[srow][1][(lane >> 4) * 4 + j][row] = acc1[j];
        }
        __syncthreads();

        // ---- activations: stage tagged h words + y/out staging (no stores) ----
        if (tid < 256) {
            const int m2 = b_ >> 4, rD = b_ & 15;
            float v0 = 0.f, v1 = 0.f, v2 = 0.f, v3 = 0.f;
            #pragma unroll
            for (int q = 0; q < 4; ++q) {
                v0 += scr[q * 2 + m2][0][rD][col_];
                v1 += scr[q * 2 + m2][0][rD][8 + col_];
                v2 += scr[q * 2 + m2][1][rD][col_];
                v3 += scr[q * 2 + m2][1][rD][8 + col_];
            }
            const float ig = 1.f / (1.f + __expf(-(v0 + bias0)));
            const float fg = 1.f / (1.f + __expf(-(v1 + bias1)));
            const float gg = tanhf(v2 + bias2);
            const float og = 1.f / (1.f + __expf(-(v3 + bias3)));
            const float cc = fg * c_s[b_][col_] + ig * gg;
            const float hh = og * tanhf(cc);
            c_s[b_][col_] = cc;

            st_hw[b_][col_] = ((unsigned)(s + 2) << 16)
                            | (unsigned)f16bits((_Float16)hh);
            if (layer == 0) st_y[b_][col_] = (_Float16)(hh * st_mi[b_][col_]);
            else            st_o[b_][col_] = hh;

            if (s == T_STEPS - 1) {
                const size_t base = (size_t)T_STEPS * BATCH * HID;
                out[base + ((size_t)layer * BATCH + b_) * HID + gcol] = hh;
                out[base + (size_t)2 * BATCH * HID
                    + ((size_t)layer * BATCH + b_) * HID + gcol] = cc;
            }
        }
        __syncthreads();

        // ---- tails ----
        if (layer == 0) {
            if (wid == 6) {
                // h0 funnel: fire-and-forget tagged u64 stores (non-polling wave)
                const int bL = lane >> 1, half = lane & 1;
                u64* dst = (u64*)(h0w + ((s + 1) & 1) * HB + bL * 1024
                                  + wgl * 8 + half * 4);
                const u64* sp = (const u64*)&st_hw[bL][half * 4];
                __hip_atomic_store(dst,     sp[0], RLX, AGT);
                __hip_atomic_store(dst + 1, sp[1], RLX, AGT);
            }
            if (tid >= 448 && tid < 480) {
                // wave 7 lower half: y0m stores -> ack -> flag0 (layer-1 feed)
                const int sl = tid - 448;
                st_coh16(&y0m[((size_t)s * BATCH + sl) * HID + wgl * 8],
                         *(const half8*)st_y[sl]);
                asm volatile("s_waitcnt vmcnt(0)" ::: "memory");
                if (tid == 448)
                    __hip_atomic_store(flag0 + wgl * 32, (unsigned)(s + 1), RLX, AGT);
            }
            if (ot >= 0 && s + 1 < T_STEPS)            // mi staging for s+1
                st_mi[b2][c2] = mi[((size_t)(s + 1) * BATCH + b2) * HID + gcol2];
            if (wid >= 4 && kq < 2 && s + 1 < T_STEPS) {   // x prefetch for s+1
                const float* xp = x + ((size_t)(s + 1) * BATCH + bb) * HID + kq * 512 + ko;
                #pragma unroll
                for (int kk = 0; kk < 16; ++kk) aF[kk] = cvt8(xp + kk * 32);
            }
        } else {
            if (wid == 2) {
                // h1 funnel (wave 2: its next-tick flag0 wait absorbs the drain)
                const int bL = lane >> 1, half = lane & 1;
                u64* dst = (u64*)(h1w + ((s + 1) & 1) * HB + bL * 1024
                                  + wgl * 8 + half * 4);
                const u64* sp = (const u64*)&st_hw[bL][half * 4];
                __hip_atomic_store(dst,     sp[0], RLX, AGT);
                __hip_atomic_store(dst + 1, sp[1], RLX, AGT);
            }
            if (ot >= 0) {
                out[((size_t)s * BATCH + b2) * HID + gcol2] = st_o[b2][c2] * mo_reg;
                if (s + 1 < T_STEPS)
                    mo_reg = mo[((size_t)(s + 1) * BATCH + b2) * HID + gcol2];
            }
        }
    }
}

extern "C" void kernel_launch(void* const* d_in, const int* in_sizes, int n_in,
                              void* d_out, int out_size, void* d_ws, size_t ws_size,
                              hipStream_t stream) {
    const float* x   = (const float*)d_in[0];
    const float* h0  = (const float*)d_in[1];
    const float* c0  = (const float*)d_in[2];
    const float* Wih = (const float*)d_in[3];
    const float* Whh = (const float*)d_in[4];
    const float* bih = (const float*)d_in[5];
    const float* bhh = (const float*)d_in[6];
    const float* mi  = (const float*)d_in[7];
    const float* mo  = (const float*)d_in[8];
    float* out = (float*)d_out;

    char* w = (char*)d_ws;
    _Float16* y0m   = (_Float16*)w;                                 // 13,107,200 B
    unsigned* h0w   = (unsigned*)(w + 13107200);                    //   262,144 B (2 slots)
    unsigned* h1w   = (unsigned*)(w + 13107200 + 262144);           //   262,144 B
    unsigned* flag0 = (unsigned*)(w + 13107200 + 524288);           //    16,384 B

    hipLaunchKernelGGL(init_k, dim3(128), dim3(256), 0, stream, h0, h0w, h1w, flag0);

    void* args[] = {(void*)&x, (void*)&c0, (void*)&Wih, (void*)&Whh,
                    (void*)&bih, (void*)&bhh, (void*)&mi, (void*)&mo,
                    (void*)&out, (void*)&y0m, (void*)&h0w, (void*)&h1w,
                    (void*)&flag0};
    hipLaunchCooperativeKernel((void*)lstm_main, dim3(NWG), dim3(NTHR),
                               args, 0, stream);
}

// Round 10
// 2738.731 us; speedup vs baseline: 1.2130x; 1.2130x over previous
//
#include <hip/hip_runtime.h>

#define T_STEPS 200
#define BATCH   32
#define HID     1024
#define NWG     256
#define NTHR    512

typedef _Float16 half8 __attribute__((ext_vector_type(8)));
typedef float    f32x4 __attribute__((ext_vector_type(4)));
typedef unsigned long long u64;

#define RLX __ATOMIC_RELAXED
#define AGT __HIP_MEMORY_SCOPE_AGENT

// Producer-side coherent (agent-scope, cache-bypassing) 16B store from two
// relaxed 8B atomics: write-through to LLC, never dirty in L2.
__device__ __forceinline__ void st_coh16(_Float16* p, half8 v) {
    union { half8 h; u64 u[2]; } r; r.h = v;
    u64* q = (u64*)p;
    __hip_atomic_store(q,     r.u[0], RLX, AGT);
    __hip_atomic_store(q + 1, r.u[1], RLX, AGT);
}

__device__ __forceinline__ half8 cvt8(const float* p) {
    f32x4 lo = *(const f32x4*)p;
    f32x4 hi = *(const f32x4*)(p + 4);
    half8 a;
    a[0] = (_Float16)lo[0]; a[1] = (_Float16)lo[1];
    a[2] = (_Float16)lo[2]; a[3] = (_Float16)lo[3];
    a[4] = (_Float16)hi[0]; a[5] = (_Float16)hi[1];
    a[6] = (_Float16)hi[2]; a[7] = (_Float16)hi[3];
    return a;
}

// ~200ns dependent-FMA backoff (kept live via asm sink)
__device__ __forceinline__ void backoff() {
    float jj = 1.0000001f;
    #pragma unroll
    for (int i = 0; i < 128; ++i)
        asm volatile("v_fma_f32 %0,%0,%0,%0" : "+v"(jj));
    asm volatile("" :: "v"(jj));
}

__global__ void init_k(const float* __restrict__ h0,
                       _Float16* __restrict__ h0b, _Float16* __restrict__ h1b,
                       unsigned* __restrict__ flag0, unsigned* __restrict__ flag1) {
    int i = blockIdx.x * blockDim.x + threadIdx.x;
    if (i < BATCH * HID) {
        h0b[i] = (_Float16)h0[i];                 // layer 0 initial h -> slot 0
        h1b[i] = (_Float16)h0[BATCH * HID + i];   // layer 1 initial h -> slot 0
    }
    if (blockIdx.x == 0 && threadIdx.x < 128) {
        flag0[threadIdx.x] = 0u;                  // PACKED: 128 words = 4 lines
        flag1[threadIdx.x] = 0u;
    }
}

// R7 structure (best: 2016us): self-timed dataflow, cached exchange reads +
// per-tick agent acquire fence (buffer_inv), producer store->ack->flag.
// R10 change: PACKED flags (4 lines instead of 128) + ONE polling wave per WG
// (64 lanes x u64-pair loads) + ~200ns backoff between failed poll rounds.
// Rationale: collapse LLC poll contention that inflates every sync RT.
__global__ __launch_bounds__(NTHR, 2) void lstm_main(
    const float* __restrict__ x, const float* __restrict__ c0,
    const float* __restrict__ Wih, const float* __restrict__ Whh,
    const float* __restrict__ bih, const float* __restrict__ bhh,
    const float* __restrict__ mi, const float* __restrict__ mo,
    float* __restrict__ out,
    _Float16* __restrict__ y0m, _Float16* __restrict__ h0b,
    _Float16* __restrict__ h1b, unsigned* __restrict__ flag0,
    unsigned* __restrict__ flag1)
{
    __shared__ _Float16 W_s[32 * 2048];     // 128 KB
    __shared__ float scr[8][2][16][17];     // per-(kq,mm) partial gate tiles
    __shared__ float c_s[BATCH][8];         // persistent cell state (f32)
    __shared__ alignas(16) _Float16 st_h[BATCH][8];  // staged h for wave-7 stores
    __shared__ alignas(16) _Float16 st_y[BATCH][8];  // staged y0*mask (layer 0)
    __shared__ float st_o[BATCH][8];        // staged h for out-stores (layer 1)

    const int bid   = blockIdx.x;
    const int layer = bid >> 7;
    const int wgl   = bid & 127;
    const int tid   = threadIdx.x;

    // ---- one-time: stage this WG's weight slice into LDS (f16, swizzled) ----
    const float* WihL = Wih + (size_t)layer * 4 * HID * HID;
    const float* WhhL = Whh + (size_t)layer * 4 * HID * HID;
    for (int idx = tid; idx < 32 * 2048; idx += NTHR) {
        int r = idx >> 11, k = idx & 2047;             // r: local gate-row
        int grow = (r >> 3) * HID + wgl * 8 + (r & 7); // global row in [4H]
        float v = (k < HID) ? WihL[(size_t)grow * HID + k]
                            : WhhL[(size_t)grow * HID + (k - HID)];
        W_s[idx ^ ((r & 7) << 3)] = (_Float16)v;       // XOR-swizzle (16B granules)
    }

    float bias0 = 0.f, bias1 = 0.f, bias2 = 0.f, bias3 = 0.f;
    int b_ = 0, col_ = 0, gcol = 0;
    if (tid < 256) {
        b_ = tid >> 3; col_ = tid & 7; gcol = wgl * 8 + col_;
        bias0 = bih[layer * 4096 + gcol]           + bhh[layer * 4096 + gcol];
        bias1 = bih[layer * 4096 + HID + gcol]     + bhh[layer * 4096 + HID + gcol];
        bias2 = bih[layer * 4096 + 2 * HID + gcol] + bhh[layer * 4096 + 2 * HID + gcol];
        bias3 = bih[layer * 4096 + 3 * HID + gcol] + bhh[layer * 4096 + 3 * HID + gcol];
        c_s[b_][col_] = c0[((size_t)layer * BATCH + b_) * HID + gcol];
    }
    // out-store / mask threads (waves 4-7): own (b2, c2)
    const int ot = tid - 256;
    const int b2 = (ot >= 0) ? (ot >> 3) : 0, c2 = (ot >= 0) ? (ot & 7) : 0;
    const int gcol2 = wgl * 8 + c2;
    __syncthreads();

    const int lane = tid & 63, wid = tid >> 6;
    // layer 0: waves 0-3 own the h-half (kq 2,3); waves 4-7 own the x-half
    // (kq 0,1, register-prefetched). layer 1: plain kq = wid>>1.
    int kq;
    if (layer == 0) kq = (wid < 4) ? (2 + (wid >> 1)) : ((wid - 4) >> 1);
    else            kq = wid >> 1;
    const int mm   = wid & 1;
    const int srow = kq * 2 + mm;          // scr slot (logical, not wid)
    const int row = lane & 15, bb = mm * 16 + row, ko = (lane >> 4) * 8;

    // ---- prefetched pure-t state ----
    half8 aF[16];
    float mi_reg = 0.f, mo_reg = 0.f;
    if (layer == 0 && kq < 2) {
        const float* xp = x + (size_t)bb * HID + kq * 512 + ko;   // s = 0
        #pragma unroll
        for (int kk = 0; kk < 16; ++kk) aF[kk] = cvt8(xp + kk * 32);
    }
    if (layer == 1 && ot >= 0) mo_reg = mo[(size_t)b2 * HID + gcol2];  // s = 0

    for (int s = 0; s < T_STEPS; ++s) {
        // ---- dataflow wait: ONE wave polls packed flags, backoff on miss ----
        if (layer == 0) {
            if (tid < 64) {
                const u64* f = (const u64*)(flag0 + 2 * tid);
                const unsigned tgt = (unsigned)s;
                const u64 tgt2 = ((u64)tgt << 32) | tgt;
                for (;;) {
                    u64 v = __hip_atomic_load(f, RLX, AGT);
                    // both 32b halves >= tgt ?
                    bool ok = ((unsigned)v >= tgt) && ((unsigned)(v >> 32) >= tgt);
                    if (__all(ok)) break;
                    backoff();
                }
                (void)tgt2;
            }
        } else {
            if (tid < 64) {
                const u64* f = (const u64*)(flag0 + 2 * tid);
                const unsigned tgt = (unsigned)(s + 1);
                for (;;) {
                    u64 v = __hip_atomic_load(f, RLX, AGT);
                    bool ok = ((unsigned)v >= tgt) && ((unsigned)(v >> 32) >= tgt);
                    if (__all(ok)) break;
                    backoff();
                }
            } else if (tid < 128) {
                const u64* f = (const u64*)(flag1 + 2 * (tid - 64));
                const unsigned tgt = (unsigned)s;
                for (;;) {
                    u64 v = __hip_atomic_load(f, RLX, AGT);
                    bool ok = ((unsigned)v >= tgt) && ((unsigned)(v >> 32) >= tgt);
                    if (__all(ok)) break;
                    backoff();
                }
            }
        }
        asm volatile("" ::: "memory");
        __syncthreads();
        // ---- acquire: invalidate L1+L2 so plain loads see the LLC data ----
        if (tid == 0) __builtin_amdgcn_fence(__ATOMIC_ACQUIRE, "agent");
        __syncthreads();

        // ---- mask load for this step (hidden under MFMA phase) ----
        if (layer == 0 && tid < 256)
            mi_reg = mi[((size_t)s * BATCH + b_) * HID + gcol];

        // ---- dependent A fragments: PLAIN CACHED loads (L2-shared fills) ----
        if (layer == 0) {
            if (kq >= 2) {
                const _Float16* hp = h0b + (s & 1) * (BATCH * HID)
                                   + bb * HID + (kq - 2) * 512 + ko;
                #pragma unroll
                for (int kk = 0; kk < 16; ++kk)
                    aF[kk] = *(const half8*)(hp + kk * 32);
            }
        } else {
            if (kq < 2) {
                const _Float16* yp = y0m + ((size_t)s * BATCH + bb) * HID + kq * 512 + ko;
                #pragma unroll
                for (int kk = 0; kk < 16; ++kk)
                    aF[kk] = *(const half8*)(yp + kk * 32);
            } else {
                const _Float16* hp = h1b + (s & 1) * (BATCH * HID)
                                   + bb * HID + (kq - 2) * 512 + ko;
                #pragma unroll
                for (int kk = 0; kk < 16; ++kk)
                    aF[kk] = *(const half8*)(hp + kk * 32);
            }
        }

        // ---- MFMA: D[batch 16][gaterow 16] x2 subtiles over K=512 ----
        f32x4 acc0 = {0.f, 0.f, 0.f, 0.f}, acc1 = {0.f, 0.f, 0.f, 0.f};
        #pragma unroll
        for (int kk = 0; kk < 16; ++kk) {
            const int k  = kq * 512 + kk * 32 + ko;
            const int r1 = 16 + row;
            const half8 bB0 = *(const half8*)&W_s[(row * 2048 + k) ^ ((row & 7) << 3)];
            const half8 bB1 = *(const half8*)&W_s[(r1 * 2048 + k) ^ ((r1 & 7) << 3)];
            acc0 = __builtin_amdgcn_mfma_f32_16x16x32_f16(aF[kk], bB0, acc0, 0, 0, 0);
            acc1 = __builtin_amdgcn_mfma_f32_16x16x32_f16(aF[kk], bB1, acc1, 0, 0, 0);
        }
        #pragma unroll
        for (int j = 0; j < 4; ++j) {
            scr[srow][0][(lane >> 4) * 4 + j][row] = acc0[j];
            scr[srow][1][(lane >> 4) * 4 + j][row] = acc1[j];
        }
        __syncthreads();

        // ---- activations: thread owns (batch b_, hidden col gcol) ----
        if (tid < 256) {
            const int m2 = b_ >> 4, rD = b_ & 15;
            float v0 = 0.f, v1 = 0.f, v2 = 0.f, v3 = 0.f;
            #pragma unroll
            for (int q = 0; q < 4; ++q) {
                v0 += scr[q * 2 + m2][0][rD][col_];       // gate i
                v1 += scr[q * 2 + m2][0][rD][8 + col_];   // gate f
                v2 += scr[q * 2 + m2][1][rD][col_];       // gate g
                v3 += scr[q * 2 + m2][1][rD][8 + col_];   // gate o
            }
            const float ig = 1.f / (1.f + __expf(-(v0 + bias0)));
            const float fg = 1.f / (1.f + __expf(-(v1 + bias1)));
            const float gg = tanhf(v2 + bias2);
            const float og = 1.f / (1.f + __expf(-(v3 + bias3)));
            const float cc = fg * c_s[b_][col_] + ig * gg;
            const float hh = og * tanhf(cc);
            c_s[b_][col_] = cc;

            st_h[b_][col_] = (_Float16)hh;
            if (layer == 0) st_y[b_][col_] = (_Float16)(hh * mi_reg);
            else            st_o[b_][col_] = hh;

            if (s == T_STEPS - 1) {
                const size_t base = (size_t)T_STEPS * BATCH * HID;
                // agent-scope stores: write-through, never dirty in L2 (inv-safe)
                __hip_atomic_store(&out[base + ((size_t)layer * BATCH + b_) * HID + gcol],
                                   hh, RLX, AGT);
                __hip_atomic_store(&out[base + (size_t)2 * BATCH * HID
                                        + ((size_t)layer * BATCH + b_) * HID + gcol],
                                   cc, RLX, AGT);
            }
        }
        __syncthreads();

        // ---- producer tails ----
        if (layer == 0) {
            if (wid >= 4) {
                if (tid >= 448 && tid < 480) {
                    // wave 7 lower half: coherent stores -> ack -> flag
                    const int sl = tid - 448;
                    st_coh16(&h0b[((s + 1) & 1) * (BATCH * HID) + sl * HID + wgl * 8],
                             *(const half8*)st_h[sl]);
                    st_coh16(&y0m[((size_t)s * BATCH + sl) * HID + wgl * 8],
                             *(const half8*)st_y[sl]);
                    asm volatile("s_waitcnt vmcnt(0)" ::: "memory");
                    if (tid == 448)
                        __hip_atomic_store(flag0 + wgl, (unsigned)(s + 1), RLX, AGT);
                }
                // x prefetch for s+1 (after the flag: ack never waits on HBM)
                if (kq < 2 && s + 1 < T_STEPS) {
                    const float* xp = x + ((size_t)(s + 1) * BATCH + bb) * HID + kq * 512 + ko;
                    #pragma unroll
                    for (int kk = 0; kk < 16; ++kk) aF[kk] = cvt8(xp + kk * 32);
                }
            }
        } else {
            if (ot >= 0) {
                // agent-scope out store: write-through (inv-safe)
                __hip_atomic_store(&out[((size_t)s * BATCH + b2) * HID + gcol2],
                                   st_o[b2][c2] * mo_reg, RLX, AGT);
                if (tid >= 448 && tid < 480) {
                    const int sl = tid - 448;
                    st_coh16(&h1b[((s + 1) & 1) * (BATCH * HID) + sl * HID + wgl * 8],
                             *(const half8*)st_h[sl]);
                    asm volatile("s_waitcnt vmcnt(0)" ::: "memory");
                    if (tid == 448)
                        __hip_atomic_store(flag1 + wgl, (unsigned)(s + 1), RLX, AGT);
                }
                if (s + 1 < T_STEPS)
                    mo_reg = mo[((size_t)(s + 1) * BATCH + b2) * HID + gcol2];
            }
        }
    }
}

extern "C" void kernel_launch(void* const* d_in, const int* in_sizes, int n_in,
                              void* d_out, int out_size, void* d_ws, size_t ws_size,
                              hipStream_t stream) {
    const float* x   = (const float*)d_in[0];
    const float* h0  = (const float*)d_in[1];
    const float* c0  = (const float*)d_in[2];
    const float* Wih = (const float*)d_in[3];
    const float* Whh = (const float*)d_in[4];
    const float* bih = (const float*)d_in[5];
    const float* bhh = (const float*)d_in[6];
    const float* mi  = (const float*)d_in[7];
    const float* mo  = (const float*)d_in[8];
    float* out = (float*)d_out;

    char* w = (char*)d_ws;
    _Float16* y0m   = (_Float16*)w;                                // 13,107,200 B
    _Float16* h0b   = (_Float16*)(w + 13107200);                   //   131,072 B (2 slots)
    _Float16* h1b   = (_Float16*)(w + 13107200 + 131072);          //   131,072 B
    unsigned* flag0 = (unsigned*)(w + 13107200 + 262144);          //       512 B (packed)
    unsigned* flag1 = (unsigned*)(w + 13107200 + 262144 + 1024);   //       512 B (packed)

    hipLaunchKernelGGL(init_k, dim3(128), dim3(256), 0, stream,
                       h0, h0b, h1b, flag0, flag1);

    void* args[] = {(void*)&x, (void*)&c0, (void*)&Wih, (void*)&Whh,
                    (void*)&bih, (void*)&bhh, (void*)&mi, (void*)&mo,
                    (void*)&out, (void*)&y0m, (void*)&h0b, (void*)&h1b,
                    (void*)&flag0, (void*)&flag1};
    hipLaunchCooperativeKernel((void*)lstm_main, dim3(NWG), dim3(NTHR),
                               args, 0, stream);
}